// Round 8
// baseline (1620.153 us; speedup 1.0000x reference)
//
#include <hip/hip_runtime.h>
#include <stdint.h>
#include <math.h>

#define BATCH 32768
#define LDIM 128
#define HID 20
#define NG 80                       // 4*HID
#define EPS_N (LDIM * BATCH)        // 4,194,304 eps values

// =====================================================================
// eps: jax.random.normal(key(42), (128,32768), f32), partitionable
// threefry (counters (0,n), output o0^o1) — VERIFIED PASSING (r4-r6,
// absmax 0.0156 = 1 bf16 ulp). Do not touch the math.
// =====================================================================

__device__ __forceinline__ void threefry2x32(uint32_t x0, uint32_t x1,
                                             uint32_t& o0, uint32_t& o1) {
  const uint32_t k0 = 0u, k1 = 42u;
  const uint32_t k2 = k0 ^ k1 ^ 0x1BD11BDAu;
  uint32_t v0 = x0 + k0, v1 = x1 + k1;
#define TF_R(r) { v0 += v1; v1 = (v1 << (r)) | (v1 >> (32 - (r))); v1 ^= v0; }
  TF_R(13) TF_R(15) TF_R(26) TF_R(6)
  v0 += k1; v1 += k2 + 1u;
  TF_R(17) TF_R(29) TF_R(16) TF_R(24)
  v0 += k2; v1 += k0 + 2u;
  TF_R(13) TF_R(15) TF_R(26) TF_R(6)
  v0 += k0; v1 += k1 + 3u;
  TF_R(17) TF_R(29) TF_R(16) TF_R(24)
  v0 += k1; v1 += k2 + 4u;
  TF_R(13) TF_R(15) TF_R(26) TF_R(6)
  v0 += k2; v1 += k0 + 5u;
#undef TF_R
  o0 = v0; o1 = v1;
}

__device__ __forceinline__ float erfinv_xla_f32(float x) {
  float t = __fmul_rn(x, x);
  float w = -(float)log1p(-(double)t);   // correctly-rounded f32 log1p
  float p;
  if (w < 5.0f) {
    w = __fadd_rn(w, -2.5f);
    p = 2.81022636e-08f;
    p = __fadd_rn(__fmul_rn(p, w), 3.43273939e-07f);
    p = __fadd_rn(__fmul_rn(p, w), -3.5233877e-06f);
    p = __fadd_rn(__fmul_rn(p, w), -4.39150654e-06f);
    p = __fadd_rn(__fmul_rn(p, w), 0.00021858087f);
    p = __fadd_rn(__fmul_rn(p, w), -0.00125372503f);
    p = __fadd_rn(__fmul_rn(p, w), -0.00417768164f);
    p = __fadd_rn(__fmul_rn(p, w), 0.246640727f);
    p = __fadd_rn(__fmul_rn(p, w), 1.50140941f);
  } else {
    w = __fadd_rn(__fsqrt_rn(w), -3.0f);
    p = -0.000200214257f;
    p = __fadd_rn(__fmul_rn(p, w), 0.000100950558f);
    p = __fadd_rn(__fmul_rn(p, w), 0.00134934322f);
    p = __fadd_rn(__fmul_rn(p, w), -0.00367342844f);
    p = __fadd_rn(__fmul_rn(p, w), 0.00573950773f);
    p = __fadd_rn(__fmul_rn(p, w), -0.0076224613f);
    p = __fadd_rn(__fmul_rn(p, w), 0.00943887047f);
    p = __fadd_rn(__fmul_rn(p, w), 1.00167406f);
    p = __fadd_rn(__fmul_rn(p, w), 2.83297682f);
  }
  return __fmul_rn(p, x);
}

__device__ __forceinline__ float eps_from_n(uint32_t n) {
  uint32_t o0, o1;
  threefry2x32(0u, n, o0, o1);
  uint32_t bits = o0 ^ o1;
  const float lo    = __uint_as_float(0xBF7FFFFFu);
  const float sqrt2 = __uint_as_float(0x3FB504F3u);
  float f = __fadd_rn(__uint_as_float((bits >> 9) | 0x3F800000u), -1.0f);
  float u = __fadd_rn(__fmul_rn(f, 2.0f), lo);
  u = fmaxf(u, lo);
  return __fmul_rn(sqrt2, erfinv_xla_f32(u));
}

// Fill d_ws with all eps values (flat n = t*32768 + b)
__global__ __launch_bounds__(256) void eps_fill_kernel(float* __restrict__ ws) {
  uint32_t base = (blockIdx.x * 256u + threadIdx.x) * 4u;
  float4 v;
  v.x = eps_from_n(base);
  v.y = eps_from_n(base + 1);
  v.z = eps_from_n(base + 2);
  v.w = eps_from_n(base + 3);
  *(float4*)(ws + base) = v;
}

__device__ __forceinline__ float fexp2(float x) { return __builtin_amdgcn_exp2f(x); }
__device__ __forceinline__ float frcp(float x)  { return __builtin_amdgcn_rcpf(x); }
__device__ __forceinline__ float fexp(float x)  { return fexp2(1.442695040888963f * x); }
__device__ __forceinline__ float sigm(float x)  { return frcp(1.0f + fexp2(-1.442695040888963f * x)); }
__device__ __forceinline__ float tanhx(float x) { return 1.0f - 2.0f * frcp(1.0f + fexp2(2.885390081777926f * x)); }

// =====================================================================
// 4 lanes per element: role = tid&3 owns k in [5*role, 5*role+5).
// W_hh1 columns are stored per-role permuted so the h all-gather needs
// only 15 xor-shuffles and no per-role selects.
// H register order: m = s*5 + kl  <->  global j = 5*(role^s) + kl.
// mu prefetch: m_cur holds mu[:, t-1] when iteration t runs (FIXED r8:
// prefetch mrow[t] at iteration t, consumed at t+1 — r7 loaded mrow[t+1],
// shifting all input columns one step late).
// =====================================================================
template <bool PRE>
__global__ __launch_bounds__(256, 2) void sampler_kernel(
    const float* __restrict__ mu, const float* __restrict__ log_var,
    const float* __restrict__ W_ih1, const float* __restrict__ W_hh1,
    const float* __restrict__ b_ih1, const float* __restrict__ b_hh1,
    const float* __restrict__ W_ih2, const float* __restrict__ W_hh2,
    const float* __restrict__ b_ih2, const float* __restrict__ b_hh2,
    const float* __restrict__ ws_eps,
    float* __restrict__ out) {
  __shared__ __align__(16) float sWih1T[127 * NG];  // [j][role*20 + type*5 + kl]
  __shared__ __align__(16) float sWhh1[1600];       // [role][type*5+klr][m] (m perm by role)
  __shared__ __align__(16) float sWih2[320];        // [role][kl][hc][j]
  __shared__ __align__(16) float sB1s[NG];          // [role*20 + type*5 + kl]
  __shared__ __align__(16) float sWhh2[16];
  __shared__ __align__(16) float sB2[8];

  const int tid = threadIdx.x;
  for (int i = tid; i < 127 * NG; i += 256) {
    int j = i / NG, q = i - j * NG;          // q = role*20 + type*5 + kl
    int role = q / 20, rem = q - role * 20;
    int type = rem / 5, kl = rem - type * 5;
    int g = type * 20 + role * 5 + kl;
    sWih1T[i] = W_ih1[g * 127 + j];
  }
  for (int i = tid; i < 1600; i += 256) {
    int m = i % 20, r = i / 20;              // r = role*20 + type*5 + klr
    int role = r / 20, rem = r - role * 20;
    int type = rem / 5, klr = rem - type * 5;
    int g = type * 20 + role * 5 + klr;
    int j = 5 * (role ^ (m / 5)) + (m % 5);  // role-permuted column
    sWhh1[i] = W_hh1[g * HID + j];
  }
  for (int i = tid; i < 320; i += 256) {
    int j = i & 7, r = i >> 3;               // r = (role*5+kl)*2 + hc
    int hc = r & 1, rk = r >> 1;
    int role = rk / 5, kl = rk - role * 5;
    sWih2[i] = W_ih2[j * 40 + hc * 20 + role * 5 + kl];
  }
  if (tid < 80) {
    int role = tid / 20, rem = tid - role * 20;
    int type = rem / 5, kl = rem - type * 5;
    int g = type * 20 + role * 5 + kl;
    sB1s[tid] = b_ih1[g] + b_hh1[g];
  }
  if (tid < 16) sWhh2[tid] = W_hh2[tid];
  if (tid < 8)  sB2[tid] = b_ih2[tid] + b_hh2[tid];
  __syncthreads();

  const int role = tid & 3;
  const int elem = blockIdx.x * 64 + (tid >> 2);
  const int rbase = role * 20;
  const float* mrow = mu + (size_t)elem * LDIM;

  // first_input (replicated across the 4 lanes of the pair)
  float eps0 = PRE ? ws_eps[elem] : eps_from_n((uint32_t)elem);
  float m0 = mrow[0];
  float fi = fmaf(eps0, fexp(0.5f * log_var[(size_t)elem * LDIM]), m0);

  // this lane's 20 gate accumulators, i = type*5 + kl
  float acc[20];
  {
    const float4* c4 = (const float4*)&sWih1T[rbase];
#pragma unroll
    for (int q = 0; q < 5; ++q) {
      float4 w4 = c4[q];
      acc[4*q]   = fi * w4.x; acc[4*q+1] = fi * w4.y;
      acc[4*q+2] = fi * w4.z; acc[4*q+3] = fi * w4.w;
    }
  }

  float H[HID];   // m-order: H[s*5+kl] = h of role (role^s), local kl
  float c[5];
#pragma unroll
  for (int k = 0; k < HID; ++k) H[k] = 0.0f;
#pragma unroll
  for (int k = 0; k < 5; ++k) c[k] = 0.0f;
  float h2a = 0.0f, h2b = 0.0f, c2a = 0.0f, c2b = 0.0f;

  float* out_mu = out;
  float* out_lv = out + (size_t)BATCH * LDIM;
  float* out_sp = out + 2 * (size_t)BATCH * LDIM;
  const size_t rowoff = (size_t)elem * LDIM;
  {
    float v0 = (role == 0) ? 0.0f : (role == 1) ? 1.0f : fi;
    float* bp = (role == 0) ? out_mu : (role == 1) ? out_lv : out_sp;
    if (role < 3) bp[rowoff] = v0;
  }

  // prefetch registers: when iteration t runs, eps_cur = eps[t], m_cur = mu[:,t-1]
  float eps_cur = PRE ? ws_eps[(size_t)BATCH + elem] : eps_from_n(32768u + (uint32_t)elem);
  float m_cur = m0;

  for (int t = 1; t < LDIM; ++t) {
    float eps_nxt = 0.0f;
    if (t < LDIM - 1) {
      eps_nxt = PRE ? ws_eps[(size_t)(t + 1) * BATCH + elem]
                    : eps_from_n((uint32_t)(t + 1) * 32768u + (uint32_t)elem);
    }
    float m_nxt = mrow[t];   // mu[:, t], consumed at iteration t+1 as mu[(t+1)-1]

    // ---- maintain acc = (input cols) @ W_ih1^T (prefix trick) ----
    if (t >= 2) {
      if (t == 2) {
        float d0 = m0 - fi;   // col 0 switches first_input -> mu[:,0]
        const float4* c4 = (const float4*)&sWih1T[rbase];
#pragma unroll
        for (int q = 0; q < 5; ++q) {
          float4 w4 = c4[q];
          acc[4*q]   = fmaf(d0, w4.x, acc[4*q]);
          acc[4*q+1] = fmaf(d0, w4.y, acc[4*q+1]);
          acc[4*q+2] = fmaf(d0, w4.z, acc[4*q+2]);
          acc[4*q+3] = fmaf(d0, w4.w, acc[4*q+3]);
        }
      }
      float xm = m_cur;   // mu[:, t-1]
      const float4* col4 = (const float4*)&sWih1T[(t - 1) * NG + rbase];
#pragma unroll
      for (int q = 0; q < 5; ++q) {
        float4 w4 = col4[q];
        acc[4*q]   = fmaf(xm, w4.x, acc[4*q]);
        acc[4*q+1] = fmaf(xm, w4.y, acc[4*q+1]);
        acc[4*q+2] = fmaf(xm, w4.z, acc[4*q+2]);
        acc[4*q+3] = fmaf(xm, w4.w, acc[4*q+3]);
      }
    }

    // ---- LSTM2 gate init (replicated) + partial accumulators ----
    float g2i[8], g2p[8];
#pragma unroll
    for (int j = 0; j < 8; ++j) {
      g2i[j] = sB2[j] + h2a * sWhh2[2 * j] + h2b * sWhh2[2 * j + 1];
      g2p[j] = 0.0f;
    }

    // ---- LSTM1: this lane's 5 k's (20 gates), fused LSTM2 partials ----
    float hn[5];
#pragma unroll
    for (int kl = 0; kl < 5; ++kl) {
      float s0 = acc[kl]      + sB1s[rbase + kl];
      float s1 = acc[5 + kl]  + sB1s[rbase + 5 + kl];
      float s2 = acc[10 + kl] + sB1s[rbase + 10 + kl];
      float s3 = acc[15 + kl] + sB1s[rbase + 15 + kl];
      const float4* wi = (const float4*)&sWhh1[(rbase + 0  + kl) * HID];
      const float4* wf = (const float4*)&sWhh1[(rbase + 5  + kl) * HID];
      const float4* wg = (const float4*)&sWhh1[(rbase + 10 + kl) * HID];
      const float4* wo = (const float4*)&sWhh1[(rbase + 15 + kl) * HID];
#pragma unroll
      for (int q = 0; q < 5; ++q) {
        float4 a = wi[q], bq = wf[q], cq = wg[q], dq = wo[q];
        float v0 = H[4*q], v1 = H[4*q+1], v2 = H[4*q+2], v3 = H[4*q+3];
        s0 = fmaf(v0, a.x, s0);  s0 = fmaf(v1, a.y, s0);
        s0 = fmaf(v2, a.z, s0);  s0 = fmaf(v3, a.w, s0);
        s1 = fmaf(v0, bq.x, s1); s1 = fmaf(v1, bq.y, s1);
        s1 = fmaf(v2, bq.z, s1); s1 = fmaf(v3, bq.w, s1);
        s2 = fmaf(v0, cq.x, s2); s2 = fmaf(v1, cq.y, s2);
        s2 = fmaf(v2, cq.z, s2); s2 = fmaf(v3, cq.w, s2);
        s3 = fmaf(v0, dq.x, s3); s3 = fmaf(v1, dq.y, s3);
        s3 = fmaf(v2, dq.z, s3); s3 = fmaf(v3, dq.w, s3);
      }
      float ik = sigm(s0), fk = sigm(s1), gk = tanhx(s2), ok = sigm(s3);
      float cn = fmaf(fk, c[kl], ik * gk);
      c[kl] = cn;
      float hk = ok * tanhx(cn);
      hn[kl] = hk;
      float lh = (hk >= 0.0f) ? hk : 0.01f * hk;
      float lc = (cn >= 0.0f) ? cn : 0.01f * cn;
      const float4* uu = (const float4*)&sWih2[((role * 5 + kl) * 2 + 0) * 8];
      const float4* vv = (const float4*)&sWih2[((role * 5 + kl) * 2 + 1) * 8];
      float4 u0 = uu[0], u1 = uu[1], v0 = vv[0], v1 = vv[1];
      g2p[0] = fmaf(lh, u0.x, g2p[0]); g2p[1] = fmaf(lh, u0.y, g2p[1]);
      g2p[2] = fmaf(lh, u0.z, g2p[2]); g2p[3] = fmaf(lh, u0.w, g2p[3]);
      g2p[4] = fmaf(lh, u1.x, g2p[4]); g2p[5] = fmaf(lh, u1.y, g2p[5]);
      g2p[6] = fmaf(lh, u1.z, g2p[6]); g2p[7] = fmaf(lh, u1.w, g2p[7]);
      g2p[0] = fmaf(lc, v0.x, g2p[0]); g2p[1] = fmaf(lc, v0.y, g2p[1]);
      g2p[2] = fmaf(lc, v0.z, g2p[2]); g2p[3] = fmaf(lc, v0.w, g2p[3]);
      g2p[4] = fmaf(lc, v1.x, g2p[4]); g2p[5] = fmaf(lc, v1.y, g2p[5]);
      g2p[6] = fmaf(lc, v1.z, g2p[6]); g2p[7] = fmaf(lc, v1.w, g2p[7]);
    }

    // ---- h all-gather across the 4 lanes (xor shuffles, m-order) ----
#pragma unroll
    for (int kl = 0; kl < 5; ++kl) {
      float a = hn[kl];
      float b = __shfl_xor(a, 1, 64);   // role^1
      float cc = __shfl_xor(a, 2, 64);  // role^2
      float d = __shfl_xor(b, 2, 64);   // role^3
      H[kl]      = a;
      H[5 + kl]  = b;
      H[10 + kl] = cc;
      H[15 + kl] = d;
    }

    // ---- LSTM2 gates: 4-lane reduce, then cell (replicated) ----
    float g2[8];
#pragma unroll
    for (int j = 0; j < 8; ++j) {
      float s = g2p[j] + __shfl_xor(g2p[j], 1, 64);
      s = s + __shfl_xor(s, 2, 64);
      g2[j] = g2i[j] + s;
    }

    float i20 = sigm(g2[0]), i21 = sigm(g2[1]);
    float f20 = sigm(g2[2]), f21 = sigm(g2[3]);
    float t20 = tanhx(g2[4]), t21 = tanhx(g2[5]);
    float o20 = sigm(g2[6]), o21 = sigm(g2[7]);
    c2a = fmaf(f20, c2a, i20 * t20);
    c2b = fmaf(f21, c2b, i21 * t21);
    h2a = o20 * tanhx(c2a);
    h2b = o21 * tanhx(c2b);

    // ---- sample + role-split store (1 masked store) ----
    float sp = fmaf(eps_cur, fexp(0.5f * h2b), h2a);
    {
      float v = (role == 0) ? h2a : (role == 1) ? h2b : sp;
      float* bp = (role == 0) ? out_mu : (role == 1) ? out_lv : out_sp;
      if (role < 3) bp[rowoff + t] = v;
    }

    eps_cur = eps_nxt;
    m_cur = m_nxt;
  }
}

extern "C" void kernel_launch(void* const* d_in, const int* in_sizes, int n_in,
                              void* d_out, int out_size, void* d_ws, size_t ws_size,
                              hipStream_t stream) {
  (void)in_sizes; (void)n_in; (void)out_size;
  const float* mu      = (const float*)d_in[0];
  const float* log_var = (const float*)d_in[1];
  const float* W_ih1   = (const float*)d_in[2];
  const float* W_hh1   = (const float*)d_in[3];
  const float* b_ih1   = (const float*)d_in[4];
  const float* b_hh1   = (const float*)d_in[5];
  const float* W_ih2   = (const float*)d_in[6];
  const float* W_hh2   = (const float*)d_in[7];
  const float* b_ih2   = (const float*)d_in[8];
  const float* b_hh2   = (const float*)d_in[9];
  float* out = (float*)d_out;

  const size_t eps_bytes = (size_t)EPS_N * sizeof(float);
  dim3 grid(BATCH / 64), block(256);   // 4 lanes per element
  if (ws_size >= eps_bytes) {
    float* ws_eps = (float*)d_ws;
    eps_fill_kernel<<<EPS_N / (256 * 4), 256, 0, stream>>>(ws_eps);
    sampler_kernel<true><<<grid, block, 0, stream>>>(
        mu, log_var, W_ih1, W_hh1, b_ih1, b_hh1, W_ih2, W_hh2, b_ih2, b_hh2,
        ws_eps, out);
  } else {
    sampler_kernel<false><<<grid, block, 0, stream>>>(
        mu, log_var, W_ih1, W_hh1, b_ih1, b_hh1, W_ih2, W_hh2, b_ih2, b_hh2,
        nullptr, out);
  }
}

// Round 9
// 1464.215 us; speedup vs baseline: 1.1065x; 1.1065x over previous
//
#include <hip/hip_runtime.h>
#include <stdint.h>
#include <math.h>

#define BATCH 32768
#define LDIM 128
#define HID 20
#define NG 80                       // 4*HID

// =====================================================================
// eps: jax.random.normal(key(42), (128,32768), f32), partitionable
// threefry (counters (0,n), output o0^o1) — VERIFIED PASSING (r4-r8,
// absmax 0.0156 = 1 bf16 ulp). Do not touch the math.
// =====================================================================

__device__ __forceinline__ void threefry2x32(uint32_t x0, uint32_t x1,
                                             uint32_t& o0, uint32_t& o1) {
  const uint32_t k0 = 0u, k1 = 42u;
  const uint32_t k2 = k0 ^ k1 ^ 0x1BD11BDAu;
  uint32_t v0 = x0 + k0, v1 = x1 + k1;
#define TF_R(r) { v0 += v1; v1 = (v1 << (r)) | (v1 >> (32 - (r))); v1 ^= v0; }
  TF_R(13) TF_R(15) TF_R(26) TF_R(6)
  v0 += k1; v1 += k2 + 1u;
  TF_R(17) TF_R(29) TF_R(16) TF_R(24)
  v0 += k2; v1 += k0 + 2u;
  TF_R(13) TF_R(15) TF_R(26) TF_R(6)
  v0 += k0; v1 += k1 + 3u;
  TF_R(17) TF_R(29) TF_R(16) TF_R(24)
  v0 += k1; v1 += k2 + 4u;
  TF_R(13) TF_R(15) TF_R(26) TF_R(6)
  v0 += k2; v1 += k0 + 5u;
#undef TF_R
  o0 = v0; o1 = v1;
}

__device__ __forceinline__ float erfinv_xla_f32(float x) {
  float t = __fmul_rn(x, x);
  float w = -(float)log1p(-(double)t);   // correctly-rounded f32 log1p
  float p;
  if (w < 5.0f) {
    w = __fadd_rn(w, -2.5f);
    p = 2.81022636e-08f;
    p = __fadd_rn(__fmul_rn(p, w), 3.43273939e-07f);
    p = __fadd_rn(__fmul_rn(p, w), -3.5233877e-06f);
    p = __fadd_rn(__fmul_rn(p, w), -4.39150654e-06f);
    p = __fadd_rn(__fmul_rn(p, w), 0.00021858087f);
    p = __fadd_rn(__fmul_rn(p, w), -0.00125372503f);
    p = __fadd_rn(__fmul_rn(p, w), -0.00417768164f);
    p = __fadd_rn(__fmul_rn(p, w), 0.246640727f);
    p = __fadd_rn(__fmul_rn(p, w), 1.50140941f);
  } else {
    w = __fadd_rn(__fsqrt_rn(w), -3.0f);
    p = -0.000200214257f;
    p = __fadd_rn(__fmul_rn(p, w), 0.000100950558f);
    p = __fadd_rn(__fmul_rn(p, w), 0.00134934322f);
    p = __fadd_rn(__fmul_rn(p, w), -0.00367342844f);
    p = __fadd_rn(__fmul_rn(p, w), 0.00573950773f);
    p = __fadd_rn(__fmul_rn(p, w), -0.0076224613f);
    p = __fadd_rn(__fmul_rn(p, w), 0.00943887047f);
    p = __fadd_rn(__fmul_rn(p, w), 1.00167406f);
    p = __fadd_rn(__fmul_rn(p, w), 2.83297682f);
  }
  return __fmul_rn(p, x);
}

__device__ __forceinline__ float eps_from_n(uint32_t n) {
  uint32_t o0, o1;
  threefry2x32(0u, n, o0, o1);
  uint32_t bits = o0 ^ o1;
  const float lo    = __uint_as_float(0xBF7FFFFFu);
  const float sqrt2 = __uint_as_float(0x3FB504F3u);
  float f = __fadd_rn(__uint_as_float((bits >> 9) | 0x3F800000u), -1.0f);
  float u = __fadd_rn(__fmul_rn(f, 2.0f), lo);
  u = fmaxf(u, lo);
  return __fmul_rn(sqrt2, erfinv_xla_f32(u));
}

__device__ __forceinline__ float fexp2(float x) { return __builtin_amdgcn_exp2f(x); }
__device__ __forceinline__ float frcp(float x)  { return __builtin_amdgcn_rcpf(x); }
__device__ __forceinline__ float fexp(float x)  { return fexp2(1.442695040888963f * x); }
__device__ __forceinline__ float sigm(float x)  { return frcp(1.0f + fexp2(-1.442695040888963f * x)); }
__device__ __forceinline__ float tanhx(float x) { return 1.0f - 2.0f * frcp(1.0f + fexp2(2.885390081777926f * x)); }

// =====================================================================
// 4 lanes per element (role = tid&3 owns k in [5*role,5*role+5)), with
// chunked LDS staging (CH=32 t-steps per chunk) so the inner loop does
// ZERO global memory traffic; outputs flushed as full 128-B lines.
// W_hh1 columns role-permuted (r8-verified): H[s*5+kl] <-> j=5*(role^s)+kl.
// sWc rows shifted by -1: row j holds W_ih1 column (32c-1+j) = col(t-1).
// =====================================================================
__global__ __launch_bounds__(256, 2) void sampler_kernel(
    const float* __restrict__ mu, const float* __restrict__ log_var,
    const float* __restrict__ W_ih1, const float* __restrict__ W_hh1,
    const float* __restrict__ b_ih1, const float* __restrict__ b_hh1,
    const float* __restrict__ W_ih2, const float* __restrict__ W_hh2,
    const float* __restrict__ b_ih2, const float* __restrict__ b_hh2,
    float* __restrict__ out) {
  __shared__ __align__(16) float sWhh1[1600];     // [role][type*5+klr][m]
  __shared__ __align__(16) float sWih2[320];      // [role][kl][hc][j]
  __shared__ __align__(16) float sB1s[NG];        // [role*20 + type*5 + kl]
  __shared__ __align__(16) float sWhh2[16];
  __shared__ __align__(16) float sB2[8];
  __shared__ __align__(16) float sWc[32 * 80];    // [jj][q]  W_ih1 col (32c-1+jj)
  __shared__ __align__(16) float sMu[32 * 65];    // [j][e]   stride 65
  __shared__ __align__(16) float sEps[32 * 65];   // [j][e]
  __shared__ __align__(16) float sOut[3 * 2080];  // [s][j][e] stride 65, s*2080

  const int tid = threadIdx.x;
  const int elem0 = blockIdx.x * 64;

  // ---- static weight staging (r8-verified layouts) ----
  for (int i = tid; i < 1600; i += 256) {
    int m = i % 20, r = i / 20;
    int role = r / 20, rem = r - role * 20;
    int type = rem / 5, klr = rem - type * 5;
    int g = type * 20 + role * 5 + klr;
    int j = 5 * (role ^ (m / 5)) + (m % 5);
    sWhh1[i] = W_hh1[g * HID + j];
  }
  for (int i = tid; i < 320; i += 256) {
    int j = i & 7, r = i >> 3;
    int hc = r & 1, rk = r >> 1;
    int role = rk / 5, kl = rk - role * 5;
    sWih2[i] = W_ih2[j * 40 + hc * 20 + role * 5 + kl];
  }
  if (tid < 80) {
    int role = tid / 20, rem = tid - role * 20;
    int type = rem / 5, kl = rem - type * 5;
    int g = type * 20 + role * 5 + kl;
    sB1s[tid] = b_ih1[g] + b_hh1[g];
  }
  if (tid < 16) sWhh2[tid] = W_hh2[tid];
  if (tid < 8)  sB2[tid] = b_ih2[tid] + b_hh2[tid];

  const int role = tid & 3;
  const int e = tid >> 2;            // elem local index 0..63
  const int elem = elem0 + e;
  const int rbase = role * 20;

  float lv0 = log_var[(size_t)elem * LDIM];   // early global load (once)

  // ---- chunk staging helper (c = chunk index) ----
  auto stage_chunk = [&](int c) {
    // mu: 64 elems x 32 cols, full-line float4 global reads
    for (int k = tid; k < 512; k += 256) {
      int ee = k >> 3, j4 = k & 7;
      float4 v = *(const float4*)&mu[(size_t)(elem0 + ee) * LDIM + c * 32 + j4 * 4];
      sMu[(j4 * 4 + 0) * 65 + ee] = v.x;
      sMu[(j4 * 4 + 1) * 65 + ee] = v.y;
      sMu[(j4 * 4 + 2) * 65 + ee] = v.z;
      sMu[(j4 * 4 + 3) * 65 + ee] = v.w;
    }
    // eps: computed in-place (no workspace, no global traffic)
    for (int k = tid; k < 2048; k += 256) {
      int j = k >> 6, ee = k & 63;
      sEps[j * 65 + ee] =
          eps_from_n((uint32_t)(c * 32 + j) * 32768u + (uint32_t)(elem0 + ee));
    }
    // W_ih1 columns (L2-hot 40KB array), role-permuted q order, shifted -1
    for (int k = tid; k < 2560; k += 256) {
      int jj = k / 80, q = k - jj * 80;
      int col = c * 32 - 1 + jj;
      int ro = q / 20, rem = q - ro * 20;
      int type = rem / 5, kl = rem - type * 5;
      int g = type * 20 + ro * 5 + kl;
      sWc[k] = (col >= 0) ? W_ih1[g * 127 + col] : 0.0f;
    }
  };

  auto flush_out = [&](int c, float* out_mu, float* out_lv, float* out_sp) {
    for (int k = tid; k < 1536; k += 256) {
      int s = k >> 9, rem = k & 511, ee = rem >> 3, j4 = rem & 7;
      float4 v;
      v.x = sOut[s * 2080 + (j4 * 4 + 0) * 65 + ee];
      v.y = sOut[s * 2080 + (j4 * 4 + 1) * 65 + ee];
      v.z = sOut[s * 2080 + (j4 * 4 + 2) * 65 + ee];
      v.w = sOut[s * 2080 + (j4 * 4 + 3) * 65 + ee];
      float* bp = (s == 0) ? out_mu : (s == 1) ? out_lv : out_sp;
      *(float4*)&bp[(size_t)(elem0 + ee) * LDIM + c * 32 + j4 * 4] = v;
    }
  };

  stage_chunk(0);
  __syncthreads();

  // ---- first_input ----
  float eps0 = sEps[e];              // eps[t=0]
  float m0 = sMu[e];                 // mu[:,0]
  float fi = fmaf(eps0, fexp(0.5f * lv0), m0);

  // acc init with W_ih1 col 0 (sWc row jj=1 in chunk 0)
  float acc[20];
  {
    const float4* c4 = (const float4*)&sWc[80 + rbase];
#pragma unroll
    for (int q = 0; q < 5; ++q) {
      float4 w4 = c4[q];
      acc[4*q]   = fi * w4.x; acc[4*q+1] = fi * w4.y;
      acc[4*q+2] = fi * w4.z; acc[4*q+3] = fi * w4.w;
    }
  }

  float H[HID], c1[5];
#pragma unroll
  for (int k = 0; k < HID; ++k) H[k] = 0.0f;
#pragma unroll
  for (int k = 0; k < 5; ++k) c1[k] = 0.0f;
  float h2a = 0.0f, h2b = 0.0f, c2a = 0.0f, c2b = 0.0f;

  float* out_mu = out;
  float* out_lv = out + (size_t)BATCH * LDIM;
  float* out_sp = out + 2 * (size_t)BATCH * LDIM;

  // t = 0 outputs into sOut row 0
  if (role < 3) {
    float v0 = (role == 0) ? 0.0f : (role == 1) ? 1.0f : fi;
    sOut[role * 2080 + e] = v0;
  }

  float m_cur = m0;   // mu[:, t-1] when iteration t runs

  for (int cch = 0; cch < 4; ++cch) {
    if (cch > 0) {
      __syncthreads();                       // chunk cch-1 compute complete
      flush_out(cch - 1, out_mu, out_lv, out_sp);
      stage_chunk(cch);
      __syncthreads();
    }
    const int jstart = (cch == 0) ? 1 : 0;
    for (int j = jstart; j < 32; ++j) {
      const int t = cch * 32 + j;

      // ---- prefix acc update: + mu[t-1] * W_ih1 col(t-1) ----
      if (t >= 2) {
        if (t == 2) {
          float d0 = m0 - fi;                // col 0 switch first_input->mu[:,0]
          const float4* c4 = (const float4*)&sWc[80 + rbase];
#pragma unroll
          for (int q = 0; q < 5; ++q) {
            float4 w4 = c4[q];
            acc[4*q]   = fmaf(d0, w4.x, acc[4*q]);
            acc[4*q+1] = fmaf(d0, w4.y, acc[4*q+1]);
            acc[4*q+2] = fmaf(d0, w4.z, acc[4*q+2]);
            acc[4*q+3] = fmaf(d0, w4.w, acc[4*q+3]);
          }
        }
        float xm = m_cur;
        const float4* col4 = (const float4*)&sWc[j * 80 + rbase];
#pragma unroll
        for (int q = 0; q < 5; ++q) {
          float4 w4 = col4[q];
          acc[4*q]   = fmaf(xm, w4.x, acc[4*q]);
          acc[4*q+1] = fmaf(xm, w4.y, acc[4*q+1]);
          acc[4*q+2] = fmaf(xm, w4.z, acc[4*q+2]);
          acc[4*q+3] = fmaf(xm, w4.w, acc[4*q+3]);
        }
      }

      // ---- LSTM2 gate init (replicated) + partials ----
      float g2i[8], g2p[8];
#pragma unroll
      for (int jj = 0; jj < 8; ++jj) {
        g2i[jj] = sB2[jj] + h2a * sWhh2[2 * jj] + h2b * sWhh2[2 * jj + 1];
        g2p[jj] = 0.0f;
      }

      // ---- LSTM1: this lane's 5 k's, fused LSTM2 partials ----
      float hn[5];
#pragma unroll
      for (int kl = 0; kl < 5; ++kl) {
        float s0 = acc[kl]      + sB1s[rbase + kl];
        float s1 = acc[5 + kl]  + sB1s[rbase + 5 + kl];
        float s2 = acc[10 + kl] + sB1s[rbase + 10 + kl];
        float s3 = acc[15 + kl] + sB1s[rbase + 15 + kl];
        const float4* wi = (const float4*)&sWhh1[(rbase + 0  + kl) * HID];
        const float4* wf = (const float4*)&sWhh1[(rbase + 5  + kl) * HID];
        const float4* wg = (const float4*)&sWhh1[(rbase + 10 + kl) * HID];
        const float4* wo = (const float4*)&sWhh1[(rbase + 15 + kl) * HID];
#pragma unroll
        for (int q = 0; q < 5; ++q) {
          float4 a = wi[q], bq = wf[q], cq = wg[q], dq = wo[q];
          float v0 = H[4*q], v1 = H[4*q+1], v2 = H[4*q+2], v3 = H[4*q+3];
          s0 = fmaf(v0, a.x, s0);  s0 = fmaf(v1, a.y, s0);
          s0 = fmaf(v2, a.z, s0);  s0 = fmaf(v3, a.w, s0);
          s1 = fmaf(v0, bq.x, s1); s1 = fmaf(v1, bq.y, s1);
          s1 = fmaf(v2, bq.z, s1); s1 = fmaf(v3, bq.w, s1);
          s2 = fmaf(v0, cq.x, s2); s2 = fmaf(v1, cq.y, s2);
          s2 = fmaf(v2, cq.z, s2); s2 = fmaf(v3, cq.w, s2);
          s3 = fmaf(v0, dq.x, s3); s3 = fmaf(v1, dq.y, s3);
          s3 = fmaf(v2, dq.z, s3); s3 = fmaf(v3, dq.w, s3);
        }
        float ik = sigm(s0), fk = sigm(s1), gk = tanhx(s2), ok = sigm(s3);
        float cn = fmaf(fk, c1[kl], ik * gk);
        c1[kl] = cn;
        float hk = ok * tanhx(cn);
        hn[kl] = hk;
        float lh = (hk >= 0.0f) ? hk : 0.01f * hk;
        float lc = (cn >= 0.0f) ? cn : 0.01f * cn;
        const float4* uu = (const float4*)&sWih2[((role * 5 + kl) * 2 + 0) * 8];
        const float4* vv = (const float4*)&sWih2[((role * 5 + kl) * 2 + 1) * 8];
        float4 u0 = uu[0], u1 = uu[1], v0 = vv[0], v1 = vv[1];
        g2p[0] = fmaf(lh, u0.x, g2p[0]); g2p[1] = fmaf(lh, u0.y, g2p[1]);
        g2p[2] = fmaf(lh, u0.z, g2p[2]); g2p[3] = fmaf(lh, u0.w, g2p[3]);
        g2p[4] = fmaf(lh, u1.x, g2p[4]); g2p[5] = fmaf(lh, u1.y, g2p[5]);
        g2p[6] = fmaf(lh, u1.z, g2p[6]); g2p[7] = fmaf(lh, u1.w, g2p[7]);
        g2p[0] = fmaf(lc, v0.x, g2p[0]); g2p[1] = fmaf(lc, v0.y, g2p[1]);
        g2p[2] = fmaf(lc, v0.z, g2p[2]); g2p[3] = fmaf(lc, v0.w, g2p[3]);
        g2p[4] = fmaf(lc, v1.x, g2p[4]); g2p[5] = fmaf(lc, v1.y, g2p[5]);
        g2p[6] = fmaf(lc, v1.z, g2p[6]); g2p[7] = fmaf(lc, v1.w, g2p[7]);
      }

      // ---- h all-gather across the 4 lanes ----
#pragma unroll
      for (int kl = 0; kl < 5; ++kl) {
        float a = hn[kl];
        float b = __shfl_xor(a, 1, 64);
        float cc = __shfl_xor(a, 2, 64);
        float d = __shfl_xor(b, 2, 64);
        H[kl]      = a;
        H[5 + kl]  = b;
        H[10 + kl] = cc;
        H[15 + kl] = d;
      }

      // ---- LSTM2 reduce + cell (replicated) ----
      float g2[8];
#pragma unroll
      for (int jj = 0; jj < 8; ++jj) {
        float s = g2p[jj] + __shfl_xor(g2p[jj], 1, 64);
        s = s + __shfl_xor(s, 2, 64);
        g2[jj] = g2i[jj] + s;
      }
      float i20 = sigm(g2[0]), i21 = sigm(g2[1]);
      float f20 = sigm(g2[2]), f21 = sigm(g2[3]);
      float t20 = tanhx(g2[4]), t21 = tanhx(g2[5]);
      float o20 = sigm(g2[6]), o21 = sigm(g2[7]);
      c2a = fmaf(f20, c2a, i20 * t20);
      c2b = fmaf(f21, c2b, i21 * t21);
      h2a = o20 * tanhx(c2a);
      h2b = o21 * tanhx(c2b);

      // ---- sample + LDS store (conflict-light) ----
      float eps_t = sEps[j * 65 + e];
      float sp = fmaf(eps_t, fexp(0.5f * h2b), h2a);
      if (role < 3) {
        float v = (role == 0) ? h2a : (role == 1) ? h2b : sp;
        sOut[role * 2080 + j * 65 + e] = v;
      }

      m_cur = sMu[j * 65 + e];   // mu[:, t], consumed next iteration
    }
  }
  __syncthreads();
  flush_out(3, out_mu, out_lv, out_sp);
}

extern "C" void kernel_launch(void* const* d_in, const int* in_sizes, int n_in,
                              void* d_out, int out_size, void* d_ws, size_t ws_size,
                              hipStream_t stream) {
  (void)in_sizes; (void)n_in; (void)out_size; (void)d_ws; (void)ws_size;
  const float* mu      = (const float*)d_in[0];
  const float* log_var = (const float*)d_in[1];
  const float* W_ih1   = (const float*)d_in[2];
  const float* W_hh1   = (const float*)d_in[3];
  const float* b_ih1   = (const float*)d_in[4];
  const float* b_hh1   = (const float*)d_in[5];
  const float* W_ih2   = (const float*)d_in[6];
  const float* W_hh2   = (const float*)d_in[7];
  const float* b_ih2   = (const float*)d_in[8];
  const float* b_hh2   = (const float*)d_in[9];
  float* out = (float*)d_out;

  dim3 grid(BATCH / 64), block(256);   // 4 lanes per element
  sampler_kernel<<<grid, block, 0, stream>>>(mu, log_var, W_ih1, W_hh1, b_ih1,
                                             b_hh1, W_ih2, W_hh2, b_ih2, b_hh2, out);
}